// Round 4
// baseline (233.495 us; speedup 1.0000x reference)
//
#include <hip/hip_runtime.h>
#include <hip/hip_bf16.h>
#include <math.h>

#define NTHREADS 256
typedef __attribute__((ext_vector_type(8))) short short8;
typedef __attribute__((ext_vector_type(4))) float f32x4;
typedef unsigned short ushort_t;

// ---- conv kernel LDS: two time-major activation buffers hT[row=t+4][slot],
// 212 rows x stride 40 bf16 (bufA/bufB), PLUS packed conv1 input X:
// 212 rows x stride 32 (slot = tap*6 + ch, 30 used), aliased INSIDE bufB at
// row 4 (X dead once conv1 done; conv2 then overwrites bufB). Total LDS
// unchanged: 33,920 B -> 4 blocks/CU.
// Channel slot PERMUTATION (conv1-3 outputs / conv2-4 A-frags):
//   slot s = q*8 + h*4 + r  holds  och = h*16 + q*4 + r   (q=s>>3,h=(s>>2)&1)
// -> epilogue is ONE ds_write_b128 per lane; B-read instruction unchanged.
#define HA    0
#define HB    8480
#define HSTR  40
#define XB    8640            // X base (hw) = HB + 4*HSTR; 212*32=6784 hw ends 15424 < 16960
#define XSTR  32
#define SMEM_HW 16960

// ws layout: 27 conv A-frags bf16 (512 hw each) at 0; F fp32 at byte 65536
// (B*192*4 bytes); tail-weight blob (float4[3245]) immediately after F:
//   [0..2400)  lw1s: [j4][50] float4 = lw1[c][4j4..4j4+3]
//   [2400..3050) lw2s: [j4][50] float4 (tail j zero-padded)
//   [3050..3245) lw3s: [j4][15] float4 (tail j zero-padded)
#define WSF_C1 0
#define WSF_C2 (2*512)
#define WSF_C3 (12*512)
#define WSF_C4 (22*512)
#define WS_F_BYTE_OFF 65536

__device__ __forceinline__ unsigned f2bf(float f) {
    unsigned u = __float_as_uint(f);
    return (u + 0x7FFFu + ((u >> 16) & 1u)) >> 16;
}

// packed f32x2 -> bf16x2 RNE; on gfx950 lowers to v_cvt_pk_bf16_f32.
__device__ __forceinline__ unsigned pack2bf(float a, float b) {
    __hip_bfloat162 h = __float22bfloat162_rn(make_float2(a, b));
    unsigned u; __builtin_memcpy(&u, &h, 4); return u;
}

// tanh-GELU, minimal-op form: gelu = x - x/(exp2(x*t)+1),
// t = 2*0.79788456*log2e * (1 + 0.044715 x^2).
__device__ __forceinline__ float gelu_fast(float x) {
    float x2 = x * x;
    float t  = fmaf(0.10294320f, x2, 2.3022082f);
    float e  = __builtin_amdgcn_exp2f(x * t);
    float r  = __builtin_amdgcn_rcpf(e + 1.0f);
    return fmaf(-x, r, x);
}

__device__ __forceinline__ float gelu_exact(float v) {
    return 0.5f * v * (1.0f + erff(v * 0.70710678118654752f));
}

#define JROT(Spp, Sqq, Spq, Sxp, Sxq, Vp0, Vq0, Vp1, Vq1, Vp2, Vq2)          \
    if (fabsf(Spq) > 1e-18f) {                                               \
        float tau = (Sqq - Spp) / (2.0f * Spq);                              \
        float tj = copysignf(1.0f, tau) / (fabsf(tau) + sqrtf(1.0f + tau*tau)); \
        float cj = 1.0f / sqrtf(1.0f + tj*tj);                               \
        float sj = tj * cj;                                                  \
        Spp -= tj * Spq; Sqq += tj * Spq; Spq = 0.0f;                        \
        float tmp0 = Sxp; Sxp = cj*tmp0 - sj*Sxq; Sxq = sj*tmp0 + cj*Sxq;    \
        float tv;                                                            \
        tv = Vp0; Vp0 = cj*tv - sj*Vq0; Vq0 = sj*tv + cj*Vq0;                \
        tv = Vp1; Vp1 = cj*tv - sj*Vq1; Vq1 = sj*tv + cj*Vq1;                \
        tv = Vp2; Vp2 = cj*tv - sj*Vq2; Vq2 = sj*tv + cj*Vq2;                \
    }

// ---- prep: conv weights -> MFMA A-frag lane order (bf16), fids 0..26.
// fids 27..33: repack tail linear weights into the contiguous blob (fp32).
__global__ void prep_kernel(const float* __restrict__ cw1,
                            const float* __restrict__ cw2,
                            const float* __restrict__ cw3,
                            const float* __restrict__ cw4,
                            const float* __restrict__ lw1,
                            const float* __restrict__ lw2,
                            const float* __restrict__ lw3,
                            ushort_t* __restrict__ ws,
                            float4* __restrict__ twb)
{
    const int fid = blockIdx.x;              // 0..33
    if (fid >= 27) {                         // tail-weight repack
        const int idx = (fid - 27) * 512 + threadIdx.x;
        if (idx < 2400) {
            int j4 = idx / 50, c = idx - 50 * j4;
            const float* p = lw1 + c * 192 + 4 * j4;
            twb[idx] = make_float4(p[0], p[1], p[2], p[3]);
        } else if (idx < 3050) {
            int r = idx - 2400, j4 = r / 50, c = r - 50 * j4;
            const float* p = lw2 + c * 50 + 4 * j4;
            float4 w;
            w.x = p[0]; w.y = p[1];
            w.z = (4 * j4 + 2 < 50) ? p[2] : 0.0f;
            w.w = (4 * j4 + 3 < 50) ? p[3] : 0.0f;
            twb[idx] = w;
        } else if (idx < 3245) {
            int r = idx - 3050, j4 = r / 15, c = r - 15 * j4;
            const float* p = lw3 + c * 50 + 4 * j4;
            float4 w;
            w.x = p[0]; w.y = p[1];
            w.z = (4 * j4 + 2 < 50) ? p[2] : 0.0f;
            w.w = (4 * j4 + 3 < 50) ? p[3] : 0.0f;
            twb[idx] = w;
        }
        return;
    }
    const int l = threadIdx.x >> 3, j = threadIdx.x & 7;
    const int lo = l & 15, q = l >> 4;
    const int k = q * 8 + j;                 // 0..31
    const int pk = ((k >> 2) & 1) * 16 + (k >> 3) * 4 + (k & 3);  // slot->och
    float v = 0.0f;
    if (fid < 2) {                           // conv1 packed-K: t=k/6, c=k%6
        int m = fid * 16 + lo;
        if (k < 30) { int t = k / 6, c = k - 6 * t; v = cw1[(m * 6 + c) * 5 + t]; }
    } else if (fid < 12) {                   // conv2
        int f = fid - 2, tap = f >> 1, Mt = f & 1, m = Mt * 16 + lo;
        v = cw2[(m * 32 + pk) * 5 + tap];
    } else if (fid < 22) {                   // conv3
        int f = fid - 12, tap = f >> 1, Mt = f & 1, m = Mt * 16 + lo;
        v = cw3[(m * 32 + pk) * 5 + tap];
    } else {                                 // conv4: M-row 0 only
        int tap = fid - 22;
        if (lo == 0) v = cw4[pk * 5 + tap];
    }
    ws[fid * 512 + l * 8 + j] = (ushort_t)f2bf(v);
}

// Permuted-slot epilogue: one ds_write_b128 per lane (slots q*8..q*8+7).
template<bool EDGE>
__device__ __forceinline__ void store_tile(
    ushort_t* __restrict__ dst, const f32x4 a0, const f32x4 a1,
    int n, int Lout, int quad)
{
    ushort_t* row = dst + (4 + n) * HSTR + quad * 8;
    if (EDGE && n >= Lout) {
        // rows for n >= Lout get ZEROS: establishes next layer's tail pad.
        *(uint4*)row = make_uint4(0u, 0u, 0u, 0u);
    } else {
        *(uint4*)row = make_uint4(
            pack2bf(gelu_fast(a0[0]), gelu_fast(a0[1])),
            pack2bf(gelu_fast(a0[2]), gelu_fast(a0[3])),
            pack2bf(gelu_fast(a1[0]), gelu_fast(a1[1])),
            pack2bf(gelu_fast(a1[2]), gelu_fast(a1[3])));
    }
}

// ---- conv2/3: process 2 tiles (pair) or 1; 5 taps, dil=3. Only tile 12
// (EDGEB) needs the row clamp / n<Lout guard: tiles 0..11 have n <= 191 <
// Lout(min 196), max read row 191+12=203 <= 211.
template<bool TWO, bool EDGEB>
__device__ __forceinline__ void conv_tiles(
    const ushort_t* __restrict__ src, ushort_t* __restrict__ dst,
    const short8 A[5][2], f32x4 b0, f32x4 b1, int Lout,
    int lo16, int quad, int t0)
{
    f32x4 acc00 = b0, acc01 = b1, acc10 = b0, acc11 = b1;
    const int n0a = t0 * 16, n0b = (t0 + 4) * 16;
    const ushort_t* pa = src + (n0a + lo16) * HSTR + quad * 8;
    const ushort_t* pb = src + (n0b + lo16) * HSTR + quad * 8;
    #pragma unroll
    for (int t = 0; t < 5; t++) {
        short8 Ba = *(const short8*)(pa + 3 * HSTR * t);
        acc00 = __builtin_amdgcn_mfma_f32_16x16x32_bf16(A[t][0], Ba, acc00, 0, 0, 0);
        acc01 = __builtin_amdgcn_mfma_f32_16x16x32_bf16(A[t][1], Ba, acc01, 0, 0, 0);
        if (TWO) {
            short8 Bb;
            if (EDGEB) {
                int rb = min(n0b + lo16 + 3 * t, 211);   // clamp: garbage lanes discarded
                Bb = *(const short8*)(src + rb * HSTR + quad * 8);
            } else {
                Bb = *(const short8*)(pb + 3 * HSTR * t);
            }
            acc10 = __builtin_amdgcn_mfma_f32_16x16x32_bf16(A[t][0], Bb, acc10, 0, 0, 0);
            acc11 = __builtin_amdgcn_mfma_f32_16x16x32_bf16(A[t][1], Bb, acc11, 0, 0, 0);
        }
    }
    store_tile<false>(dst, acc00, acc01, n0a + lo16, Lout, quad);
    if (TWO) store_tile<EDGEB>(dst, acc10, acc11, n0b + lo16, Lout, quad);
}

// 13 tiles over 4 waves: wave0 {0,4} {8,12e}; wave w {w,w+4} {w+8}.
template<int LAYER>
__device__ __forceinline__ void conv_mfma(
    const ushort_t* __restrict__ src, ushort_t* __restrict__ dst,
    const ushort_t* __restrict__ wsf, const float* __restrict__ bias,
    int Lout, int lane, int wave)
{
    const int lo16 = lane & 15, quad = lane >> 4;
    short8 A[5][2];
    #pragma unroll
    for (int t = 0; t < 5; t++) {
        A[t][0] = *(const short8*)(wsf + (t * 2 + 0) * 512 + lane * 8);
        A[t][1] = *(const short8*)(wsf + (t * 2 + 1) * 512 + lane * 8);
    }
    f32x4 b0, b1;
    #pragma unroll
    for (int r = 0; r < 4; r++) { b0[r] = bias[quad * 4 + r]; b1[r] = bias[16 + quad * 4 + r]; }
    conv_tiles<true, false>(src, dst, A, b0, b1, Lout, lo16, quad, wave);
    if (wave == 0) conv_tiles<true, true>(src, dst, A, b0, b1, Lout, lo16, quad, 8);
    else           conv_tiles<false, false>(src, dst, A, b0, b1, Lout, lo16, quad, wave + 8);
}

// ---- conv1 packed-K: one B-read + 2 MFMA per 16-time tile (5 taps x 6 ch
// packed into K=30<=32). Tiles {w, w+4, w+8} per wave; wave0 also edge 12.
__device__ __forceinline__ void conv1_packed(
    const ushort_t* __restrict__ xb, ushort_t* __restrict__ dst,
    const ushort_t* __restrict__ wsf, const float* __restrict__ bias,
    int lane, int wave)
{
    const int lo16 = lane & 15, quad = lane >> 4;
    const short8 A0 = *(const short8*)(wsf + 0 * 512 + lane * 8);
    const short8 A1 = *(const short8*)(wsf + 1 * 512 + lane * 8);
    f32x4 b0, b1;
    #pragma unroll
    for (int r = 0; r < 4; r++) { b0[r] = bias[quad * 4 + r]; b1[r] = bias[16 + quad * 4 + r]; }
    f32x4 a0[3], a1[3];
    #pragma unroll
    for (int u = 0; u < 3; u++) {
        const int n = (wave + 4 * u) * 16 + lo16;
        short8 B = *(const short8*)(xb + n * XSTR + quad * 8);
        a0[u] = __builtin_amdgcn_mfma_f32_16x16x32_bf16(A0, B, b0, 0, 0, 0);
        a1[u] = __builtin_amdgcn_mfma_f32_16x16x32_bf16(A1, B, b1, 0, 0, 0);
    }
    #pragma unroll
    for (int u = 0; u < 3; u++)
        store_tile<false>(dst, a0[u], a1[u], (wave + 4 * u) * 16 + lo16, 204, quad);
    if (wave == 0) {                         // edge tile 12: rows <= 207 valid
        const int n = 192 + lo16;
        short8 B = *(const short8*)(xb + n * XSTR + quad * 8);
        f32x4 e0 = __builtin_amdgcn_mfma_f32_16x16x32_bf16(A0, B, b0, 0, 0, 0);
        f32x4 e1 = __builtin_amdgcn_mfma_f32_16x16x32_bf16(A1, B, b1, 0, 0, 0);
        store_tile<true>(dst, e0, e1, n, 204, quad);
    }
}

__global__ void __launch_bounds__(NTHREADS, 4)
rminet_conv_kernel(const float* __restrict__ x,
                   const float* __restrict__ calib,
                   const float* __restrict__ biasv,
                   const float* __restrict__ cb1, const float* __restrict__ cb2,
                   const float* __restrict__ cb3, const float* __restrict__ cb4,
                   const ushort_t* __restrict__ wsp,
                   float* __restrict__ F)
{
    __shared__ __align__(16) ushort_t smh[SMEM_HW];
    const int tid  = threadIdx.x;
    const int b    = blockIdx.x;
    const int lane = tid & 63;
    const int wave = __builtin_amdgcn_readfirstlane(tid >> 6);

    // Zero (uint4 idx = hw/8): bufA pad rows 0..3 [0..19], bufA rows 200..211
    // [1000..1059] (replay-stability: proven necessary in R9/R10), bufB rows
    // 0..3 + X region [1060..1927], bufB rows 204..211 [2080..2119].
    // MFMA 0*NaN = NaN; every readable byte inits.
    {
        uint4* p = (uint4*)smh;
        for (int i = tid; i < 988; i += NTHREADS) {
            int idx = (i < 20) ? i
                    : (i < 80) ? 1000 + (i - 20)
                    : (i < 948) ? 1060 + (i - 80)
                    : 2080 + (i - 948);
            p[idx] = make_uint4(0u, 0u, 0u, 0u);
        }
    }
    __syncthreads();

    // calibrate + normalize -> packed X rows: X[rb][t*6+c] = xn[rb-4+t][c].
    // Thread tid owns xn[tid], writes rows rb = tid+4-t for t=0..4 (3 dwords
    // each). t-rotation by (tid&3) breaks the 2-bank write conflict.
    if (tid < 200) {
        const float* xc = x + (size_t)b * 1400 + 200 + tid;
        float v[6];
        #pragma unroll
        for (int ch = 0; ch < 6; ch++) v[ch] = xc[ch * 200];
        const float MEANS[6]  = {0.042766f, 0.0081577f, -0.015818f, 9.2993f, -0.087913f, -3.3231f};
        const float INVSTD[6] = {1.f/0.4142f, 1.f/0.3522f, 1.f/0.2881f, 1.f/1.474f, 1.f/0.6553f, 1.f/0.8728f};
        float xn[6];
        #pragma unroll
        for (int i = 0; i < 6; i++) {
            float acc = biasv[i];
            #pragma unroll
            for (int jj = 0; jj < 6; jj++) {
                float m = calib[i * 6 + jj] + ((i == jj) ? 1.0f : 0.0f);
                acc = fmaf(m, v[jj], acc);
            }
            xn[i] = (acc - MEANS[i]) * INVSTD[i];
        }
        const unsigned d0 = pack2bf(xn[0], xn[1]);
        const unsigned d1 = pack2bf(xn[2], xn[3]);
        const unsigned d2 = pack2bf(xn[4], xn[5]);
        const int trot = tid & 3;
        #pragma unroll
        for (int tt = 0; tt < 5; tt++) {
            int t = tt + trot; if (t >= 5) t -= 5;
            ushort_t* qp = smh + XB + (tid + 4 - t) * XSTR + t * 6;
            *(unsigned*)(qp + 0) = d0;
            *(unsigned*)(qp + 2) = d1;
            *(unsigned*)(qp + 4) = d2;
        }
    }
    __syncthreads();

    conv1_packed(smh + XB, smh + HA, wsp + WSF_C1, cb1, lane, wave);
    __syncthreads();
    conv_mfma<2>(smh + HA, smh + HB, wsp + WSF_C2, cb2, 200, lane, wave);
    __syncthreads();
    conv_mfma<3>(smh + HB, smh + HA, wsp + WSF_C3, cb3, 196, lane, wave);
    // Re-zero bufA rows 200..203 before conv4 (stale-h1 guard; disjoint from
    // conv3's writes). Kept verbatim (replay-stability proven).
    if (tid < 20) ((uint4*)smh)[1000 + tid] = make_uint4(0u, 0u, 0u, 0u);
    __syncthreads();

    // conv4 (MFMA, M-row 0 only): h3 -> F[b][192]; 12 tiles over 4 waves:
    // tile = wave + 4*u, u=0..2. Max read row 203.
    {
        const int lo16 = lane & 15, quad = lane >> 4;
        short8 A4[5];
        #pragma unroll
        for (int t = 0; t < 5; t++)
            A4[t] = *(const short8*)(wsp + WSF_C4 + t * 512 + lane * 8);
        f32x4 acc[3];
        #pragma unroll
        for (int u = 0; u < 3; u++) acc[u] = (f32x4){0.f, 0.f, 0.f, 0.f};
        const ushort_t* p4[3];
        #pragma unroll
        for (int u = 0; u < 3; u++)
            p4[u] = smh + HA + ((wave + 4 * u) * 16 + lo16) * HSTR + quad * 8;
        #pragma unroll
        for (int t = 0; t < 5; t++) {
            #pragma unroll
            for (int u = 0; u < 3; u++) {
                short8 B = *(const short8*)(p4[u] + 3 * HSTR * t);   // row <= 203
                acc[u] = __builtin_amdgcn_mfma_f32_16x16x32_bf16(A4[t], B, acc[u], 0, 0, 0);
            }
        }
        if (quad == 0) {
            const float c4 = cb4[0];
            #pragma unroll
            for (int u = 0; u < 3; u++) {
                int n = (wave + 4 * u) * 16 + lo16;
                F[(size_t)b * 192 + n] = gelu_fast(acc[u][0] + c4);
            }
        }
    }
}

// ---- tail v4: 16 items/block -> 512 blocks. LDS slimmed 68.6KB -> ~18KB:
// lw1 read from global (prep-repacked [j4][50] float4, L1/L2-resident),
// F read from global via wave-uniform (scalar) loads, lw2/lw3 staged from
// the pre-baked blob (contiguous copy, no div/mod). launch_bounds(256,6):
// 6 blocks/CU = 24 waves/CU (was 2 blocks/8 waves). GEMV math unchanged.
#define TLW2q 0
#define TLW3q 650
#define TZ1F  3380
#define TZVF  4212
#define TSM_FLOATS 4484

__global__ void __launch_bounds__(256, 6)
rminet_tail_kernel(const float* __restrict__ F,
                   const float4* __restrict__ twb,
                   const float* __restrict__ lb1,
                   const float* __restrict__ lb2,
                   const float* __restrict__ lb3,
                   float* __restrict__ out)
{
    __shared__ __align__(16) float smf[TSM_FLOATS];
    float4* smq = (float4*)smf;
    const int tid  = threadIdx.x;
    const int lane = tid & 63;
    const int g    = __builtin_amdgcn_readfirstlane(tid >> 6);
    const int i0   = blockIdx.x * 16;
    const int ib   = g * 4;

    // stage lw2s+lw3s from blob (845 contiguous float4) + zero z-pad cols
    for (int idx = tid; idx < 845; idx += 256) smq[idx] = twb[2400 + idx];
    if (tid < 32) smf[TZ1F + (tid >> 1) * 52 + 50 + (tid & 1)] = 0.0f;
    __syncthreads();

    const int cc = min(lane, 49);
    const float4* Fq = (const float4*)F;

    {   // linear1: 192 -> 50 ; w from global blob, f scalar-uniform from global
        const float4* lw1q = twb;
        float a0, a1, a2, a3;
        a0 = a1 = a2 = a3 = lb1[cc];
        for (int j4 = 0; j4 < 48; j4++) {
            float4 w = lw1q[j4 * 50 + cc];
            float4 f0 = Fq[(size_t)(i0 + ib + 0) * 48 + j4];
            float4 f1 = Fq[(size_t)(i0 + ib + 1) * 48 + j4];
            float4 f2 = Fq[(size_t)(i0 + ib + 2) * 48 + j4];
            float4 f3 = Fq[(size_t)(i0 + ib + 3) * 48 + j4];
            a0 = fmaf(w.x, f0.x, fmaf(w.y, f0.y, fmaf(w.z, f0.z, fmaf(w.w, f0.w, a0))));
            a1 = fmaf(w.x, f1.x, fmaf(w.y, f1.y, fmaf(w.z, f1.z, fmaf(w.w, f1.w, a1))));
            a2 = fmaf(w.x, f2.x, fmaf(w.y, f2.y, fmaf(w.z, f2.z, fmaf(w.w, f2.w, a2))));
            a3 = fmaf(w.x, f3.x, fmaf(w.y, f3.y, fmaf(w.z, f3.z, fmaf(w.w, f3.w, a3))));
        }
        if (lane < 50) {
            smf[TZ1F + (ib + 0) * 52 + lane] = gelu_exact(a0);
            smf[TZ1F + (ib + 1) * 52 + lane] = gelu_exact(a1);
            smf[TZ1F + (ib + 2) * 52 + lane] = gelu_exact(a2);
            smf[TZ1F + (ib + 3) * 52 + lane] = gelu_exact(a3);
        }
    }

    {   // linear2: 50 -> 50 (in-place; reads precede writes in wave order)
        float a0, a1, a2, a3;
        a0 = a1 = a2 = a3 = lb2[cc];
        for (int j4 = 0; j4 < 13; j4++) {
            float4 w = smq[TLW2q + j4 * 50 + cc];
            float4 z0 = *(const float4*)&smf[TZ1F + (ib + 0) * 52 + 4 * j4];
            float4 z1 = *(const float4*)&smf[TZ1F + (ib + 1) * 52 + 4 * j4];
            float4 z2 = *(const float4*)&smf[TZ1F + (ib + 2) * 52 + 4 * j4];
            float4 z3 = *(const float4*)&smf[TZ1F + (ib + 3) * 52 + 4 * j4];
            a0 = fmaf(w.x, z0.x, fmaf(w.y, z0.y, fmaf(w.z, z0.z, fmaf(w.w, z0.w, a0))));
            a1 = fmaf(w.x, z1.x, fmaf(w.y, z1.y, fmaf(w.z, z1.z, fmaf(w.w, z1.w, a1))));
            a2 = fmaf(w.x, z2.x, fmaf(w.y, z2.y, fmaf(w.z, z2.z, fmaf(w.w, z2.w, a2))));
            a3 = fmaf(w.x, z3.x, fmaf(w.y, z3.y, fmaf(w.z, z3.z, fmaf(w.w, z3.w, a3))));
        }
        if (lane < 50) {
            smf[TZ1F + (ib + 0) * 52 + lane] = gelu_exact(a0);
            smf[TZ1F + (ib + 1) * 52 + lane] = gelu_exact(a1);
            smf[TZ1F + (ib + 2) * 52 + lane] = gelu_exact(a2);
            smf[TZ1F + (ib + 3) * 52 + lane] = gelu_exact(a3);
        }
    }

    {   // linear3: 50 -> 15, *100 -> ZV (stride 17)
        const int c3 = min(lane, 14);
        float a0, a1, a2, a3;
        a0 = a1 = a2 = a3 = lb3[c3];
        for (int j4 = 0; j4 < 13; j4++) {
            float4 w = smq[TLW3q + j4 * 15 + c3];
            float4 z0 = *(const float4*)&smf[TZ1F + (ib + 0) * 52 + 4 * j4];
            float4 z1 = *(const float4*)&smf[TZ1F + (ib + 1) * 52 + 4 * j4];
            float4 z2 = *(const float4*)&smf[TZ1F + (ib + 2) * 52 + 4 * j4];
            float4 z3 = *(const float4*)&smf[TZ1F + (ib + 3) * 52 + 4 * j4];
            a0 = fmaf(w.x, z0.x, fmaf(w.y, z0.y, fmaf(w.z, z0.z, fmaf(w.w, z0.w, a0))));
            a1 = fmaf(w.x, z1.x, fmaf(w.y, z1.y, fmaf(w.z, z1.z, fmaf(w.w, z1.w, a1))));
            a2 = fmaf(w.x, z2.x, fmaf(w.y, z2.y, fmaf(w.z, z2.z, fmaf(w.w, z2.w, a2))));
            a3 = fmaf(w.x, z3.x, fmaf(w.y, z3.y, fmaf(w.z, z3.z, fmaf(w.w, z3.w, a3))));
        }
        if (lane < 15) {
            smf[TZVF + (ib + 0) * 17 + lane] = a0 * 100.0f;
            smf[TZVF + (ib + 1) * 17 + lane] = a1 * 100.0f;
            smf[TZVF + (ib + 2) * 17 + lane] = a2 * 100.0f;
            smf[TZVF + (ib + 3) * 17 + lane] = a3 * 100.0f;
        }
    }
    __syncthreads();

    if (g == 0 && lane < 16) {
        const float* zv = &smf[TZVF + lane * 17];
        float* ob = out + (size_t)(i0 + lane) * 15;
        #pragma unroll
        for (int c = 9; c < 15; c++) ob[c] = zv[c];

        const float A00 = zv[0], A01 = zv[1], A02 = zv[2];
        const float A10 = zv[3], A11 = zv[4], A12 = zv[5];
        const float A20 = zv[6], A21 = zv[7], A22 = zv[8];
        float S00 = A00*A00 + A10*A10 + A20*A20;
        float S01 = A00*A01 + A10*A11 + A20*A21;
        float S02 = A00*A02 + A10*A12 + A20*A22;
        float S11 = A01*A01 + A11*A11 + A21*A21;
        float S12 = A01*A02 + A11*A12 + A21*A22;
        float S22 = A02*A02 + A12*A12 + A22*A22;
        float V00=1.f, V01=0.f, V02=0.f;
        float V10=0.f, V11=1.f, V12=0.f;
        float V20=0.f, V21=0.f, V22=1.f;
        #pragma unroll
        for (int sweep = 0; sweep < 8; sweep++) {
            JROT(S00, S11, S01, S02, S12, V00, V01, V10, V11, V20, V21)
            JROT(S00, S22, S02, S01, S12, V00, V02, V10, V12, V20, V22)
            JROT(S11, S22, S12, S01, S02, V01, V02, V11, V12, V21, V22)
        }
        float e0 = S00, e1 = S11, e2 = S22;
        float va0=V00, va1=V10, va2=V20;
        float vb0=V01, vb1=V11, vb2=V21;
        float vc0=V02, vc1=V12, vc2=V22;
        float sgn = 1.0f, tq;
        if (e0 < e1) { tq=e0;e0=e1;e1=tq; tq=va0;va0=vb0;vb0=tq; tq=va1;va1=vb1;vb1=tq; tq=va2;va2=vb2;vb2=tq; sgn=-sgn; }
        if (e1 < e2) { tq=e1;e1=e2;e2=tq; tq=vb0;vb0=vc0;vc0=tq; tq=vb1;vb1=vc1;vc1=tq; tq=vb2;vb2=vc2;vc2=tq; sgn=-sgn; }
        if (e0 < e1) { tq=e0;e0=e1;e1=tq; tq=va0;va0=vb0;vb0=tq; tq=va1;va1=vb1;vb1=tq; tq=va2;va2=vb2;vb2=tq; sgn=-sgn; }
        vc0 *= sgn; vc1 *= sgn; vc2 *= sgn;
        float u10 = A00*va0 + A01*va1 + A02*va2;
        float u11 = A10*va0 + A11*va1 + A12*va2;
        float u12 = A20*va0 + A21*va1 + A22*va2;
        float n1 = sqrtf(u10*u10 + u11*u11 + u12*u12);
        float rn1 = (n1 > 1e-20f) ? 1.0f / n1 : 0.0f;
        u10 *= rn1; u11 *= rn1; u12 *= rn1;
        float u20 = A00*vb0 + A01*vb1 + A02*vb2;
        float u21 = A10*vb0 + A11*vb1 + A12*vb2;
        float u22 = A20*vb0 + A21*vb1 + A22*vb2;
        float d12 = u20*u10 + u21*u11 + u22*u12;
        u20 -= d12*u10; u21 -= d12*u11; u22 -= d12*u12;
        float n2 = sqrtf(u20*u20 + u21*u21 + u22*u22);
        float rn2 = (n2 > 1e-20f) ? 1.0f / n2 : 0.0f;
        u20 *= rn2; u21 *= rn2; u22 *= rn2;
        float u30 = u11*u22 - u12*u21;
        float u31 = u12*u20 - u10*u22;
        float u32 = u10*u21 - u11*u20;
        ob[0] = u10*va0 + u20*vb0 + u30*vc0;
        ob[1] = u10*va1 + u20*vb1 + u30*vc1;
        ob[2] = u10*va2 + u20*vb2 + u30*vc2;
        ob[3] = u11*va0 + u21*vb0 + u31*vc0;
        ob[4] = u11*va1 + u21*vb1 + u31*vc1;
        ob[5] = u11*va2 + u21*vb2 + u31*vc2;
        ob[6] = u12*va0 + u22*vb0 + u32*vc0;
        ob[7] = u12*va1 + u22*vb1 + u32*vc1;
        ob[8] = u12*va2 + u22*vb2 + u32*vc2;
    }
}

extern "C" void kernel_launch(void* const* d_in, const int* in_sizes, int n_in,
                              void* d_out, int out_size, void* d_ws, size_t ws_size,
                              hipStream_t stream) {
    (void)n_in; (void)out_size; (void)ws_size;
    const float* x     = (const float*)d_in[0];
    const float* calib = (const float*)d_in[1];
    const float* biasv = (const float*)d_in[2];
    const float* cw1   = (const float*)d_in[3];
    const float* cb1   = (const float*)d_in[4];
    const float* cw2   = (const float*)d_in[5];
    const float* cb2   = (const float*)d_in[6];
    const float* cw3   = (const float*)d_in[7];
    const float* cb3   = (const float*)d_in[8];
    const float* cw4   = (const float*)d_in[9];
    const float* cb4   = (const float*)d_in[10];
    const float* lw1   = (const float*)d_in[11];
    const float* lb1   = (const float*)d_in[12];
    const float* lw2   = (const float*)d_in[13];
    const float* lb2   = (const float*)d_in[14];
    const float* lw3   = (const float*)d_in[15];
    const float* lb3   = (const float*)d_in[16];
    float* out = (float*)d_out;
    ushort_t* wsh = (ushort_t*)d_ws;
    const int B = in_sizes[0] / 1400;
    float* Fb = (float*)((char*)d_ws + WS_F_BYTE_OFF);
    float4* twb = (float4*)((char*)d_ws + WS_F_BYTE_OFF + (size_t)B * 768);

    hipLaunchKernelGGL(prep_kernel, dim3(34), dim3(512), 0, stream,
                       cw1, cw2, cw3, cw4, lw1, lw2, lw3, wsh, twb);
    hipLaunchKernelGGL(rminet_conv_kernel, dim3(B), dim3(NTHREADS), 0, stream,
                       x, calib, biasv, cb1, cb2, cb3, cb4,
                       (const ushort_t*)wsh, Fb);
    hipLaunchKernelGGL(rminet_tail_kernel, dim3(B / 16), dim3(256), 0, stream,
                       (const float*)Fb, (const float4*)twb, lb1, lb2, lb3, out);
}

// Round 6
// 208.620 us; speedup vs baseline: 1.1192x; 1.1192x over previous
//
#include <hip/hip_runtime.h>
#include <hip/hip_bf16.h>
#include <math.h>

#define NTHREADS 256
typedef __attribute__((ext_vector_type(8))) short short8;
typedef __attribute__((ext_vector_type(4))) float f32x4;
typedef unsigned short ushort_t;

// ---- conv kernel LDS: two time-major activation buffers hT[row=t+4][slot],
// 212 rows x stride 40 bf16 (bufA/bufB). Packed conv1 input X lives IN bufB
// at the SAME 40-slot stride, base HB (slots 0..29 = tap*6+ch; 30..39 zero):
// X reads get the conflict-free HSTR=40 bank pattern (R3's XSTR=32 layout was
// an 8-way conflict). X rows 0..3 ALIAS bufB's left-pad rows -> after conv1
// consumes X, rows 0..3 are RE-ZEROED during the conv2 phase (conv2 touches
// only rows 4+; barrier after conv2 orders the zero before conv3's pad
// reads). R5's failure was exactly this aliasing, unfixed.
// Total LDS 33,920 B -> 4 blocks/CU.
// Channel slot PERMUTATION (conv1-3 outputs / conv2-4 A-frags):
//   slot s = q*8 + h*4 + r  holds  och = h*16 + q*4 + r   (q=s>>3,h=(s>>2)&1)
// -> epilogue is ONE ds_write_b128 per lane; B-read instruction unchanged.
#define HA    0
#define HB    8480
#define HSTR  40
#define SMEM_HW 16960

// ws layout: 27 conv A-frags bf16 (512 hw each) at 0; F fp32 at byte 65536.
#define WSF_C1 0
#define WSF_C2 (2*512)
#define WSF_C3 (12*512)
#define WSF_C4 (22*512)
#define WS_F_BYTE_OFF 65536

__device__ __forceinline__ unsigned f2bf(float f) {
    unsigned u = __float_as_uint(f);
    return (u + 0x7FFFu + ((u >> 16) & 1u)) >> 16;
}

// packed f32x2 -> bf16x2 RNE; on gfx950 lowers to v_cvt_pk_bf16_f32.
__device__ __forceinline__ unsigned pack2bf(float a, float b) {
    __hip_bfloat162 h = __float22bfloat162_rn(make_float2(a, b));
    unsigned u; __builtin_memcpy(&u, &h, 4); return u;
}

// tanh-GELU, minimal-op form: gelu = x - x/(exp2(x*t)+1),
// t = 2*0.79788456*log2e * (1 + 0.044715 x^2).
__device__ __forceinline__ float gelu_fast(float x) {
    float x2 = x * x;
    float t  = fmaf(0.10294320f, x2, 2.3022082f);
    float e  = __builtin_amdgcn_exp2f(x * t);
    float r  = __builtin_amdgcn_rcpf(e + 1.0f);
    return fmaf(-x, r, x);
}

__device__ __forceinline__ float gelu_exact(float v) {
    return 0.5f * v * (1.0f + erff(v * 0.70710678118654752f));
}

#define JROT(Spp, Sqq, Spq, Sxp, Sxq, Vp0, Vq0, Vp1, Vq1, Vp2, Vq2)          \
    if (fabsf(Spq) > 1e-18f) {                                               \
        float tau = (Sqq - Spp) / (2.0f * Spq);                              \
        float tj = copysignf(1.0f, tau) / (fabsf(tau) + sqrtf(1.0f + tau*tau)); \
        float cj = 1.0f / sqrtf(1.0f + tj*tj);                               \
        float sj = tj * cj;                                                  \
        Spp -= tj * Spq; Sqq += tj * Spq; Spq = 0.0f;                        \
        float tmp0 = Sxp; Sxp = cj*tmp0 - sj*Sxq; Sxq = sj*tmp0 + cj*Sxq;    \
        float tv;                                                            \
        tv = Vp0; Vp0 = cj*tv - sj*Vq0; Vq0 = sj*tv + cj*Vq0;                \
        tv = Vp1; Vp1 = cj*tv - sj*Vq1; Vq1 = sj*tv + cj*Vq1;                \
        tv = Vp2; Vp2 = cj*tv - sj*Vq2; Vq2 = sj*tv + cj*Vq2;                \
    }

// ---- prep: repack conv weights into MFMA A-frag lane order (bf16).
// A[lane l, elem j] = W[M = Mt*16 + (l&15)][K = (l>>4)*8 + j].
// conv2/3/4 K-dim is PERMUTED to match the producer's slot layout.
// conv1 K-dim is the packed (tap,ch): k = t*6+c, k<30.
__global__ void prep_kernel(const float* __restrict__ cw1,
                            const float* __restrict__ cw2,
                            const float* __restrict__ cw3,
                            const float* __restrict__ cw4,
                            ushort_t* __restrict__ ws)
{
    const int fid = blockIdx.x;              // 0..26
    const int l = threadIdx.x >> 3, j = threadIdx.x & 7;
    const int lo = l & 15, q = l >> 4;
    const int k = q * 8 + j;                 // 0..31
    const int pk = ((k >> 2) & 1) * 16 + (k >> 3) * 4 + (k & 3);  // slot->och
    float v = 0.0f;
    if (fid < 2) {                           // conv1 packed-K: t=k/6, c=k%6
        int m = fid * 16 + lo;
        if (k < 30) { int t = k / 6, c = k - 6 * t; v = cw1[(m * 6 + c) * 5 + t]; }
    } else if (fid < 12) {                   // conv2
        int f = fid - 2, tap = f >> 1, Mt = f & 1, m = Mt * 16 + lo;
        v = cw2[(m * 32 + pk) * 5 + tap];
    } else if (fid < 22) {                   // conv3
        int f = fid - 12, tap = f >> 1, Mt = f & 1, m = Mt * 16 + lo;
        v = cw3[(m * 32 + pk) * 5 + tap];
    } else {                                 // conv4: M-row 0 only
        int tap = fid - 22;
        if (lo == 0) v = cw4[pk * 5 + tap];
    }
    ws[fid * 512 + l * 8 + j] = (ushort_t)f2bf(v);
}

// Permuted-slot epilogue: one ds_write_b128 per lane (slots q*8..q*8+7).
template<bool EDGE>
__device__ __forceinline__ void store_tile(
    ushort_t* __restrict__ dst, const f32x4 a0, const f32x4 a1,
    int n, int Lout, int quad)
{
    ushort_t* row = dst + (4 + n) * HSTR + quad * 8;
    if (EDGE && n >= Lout) {
        // rows for n >= Lout get ZEROS: establishes next layer's tail pad.
        *(uint4*)row = make_uint4(0u, 0u, 0u, 0u);
    } else {
        *(uint4*)row = make_uint4(
            pack2bf(gelu_fast(a0[0]), gelu_fast(a0[1])),
            pack2bf(gelu_fast(a0[2]), gelu_fast(a0[3])),
            pack2bf(gelu_fast(a1[0]), gelu_fast(a1[1])),
            pack2bf(gelu_fast(a1[2]), gelu_fast(a1[3])));
    }
}

// ---- conv2/3: process 2 tiles (pair) or 1; 5 taps, dil=3. Only tile 12
// (EDGEB) needs the row clamp / n<Lout guard: tiles 0..11 have n <= 191 <
// Lout(min 196), max read row 191+12=203 <= 211.
template<bool TWO, bool EDGEB>
__device__ __forceinline__ void conv_tiles(
    const ushort_t* __restrict__ src, ushort_t* __restrict__ dst,
    const short8 A[5][2], f32x4 b0, f32x4 b1, int Lout,
    int lo16, int quad, int t0)
{
    f32x4 acc00 = b0, acc01 = b1, acc10 = b0, acc11 = b1;
    const int n0a = t0 * 16, n0b = (t0 + 4) * 16;
    const ushort_t* pa = src + (n0a + lo16) * HSTR + quad * 8;
    const ushort_t* pb = src + (n0b + lo16) * HSTR + quad * 8;
    #pragma unroll
    for (int t = 0; t < 5; t++) {
        short8 Ba = *(const short8*)(pa + 3 * HSTR * t);
        acc00 = __builtin_amdgcn_mfma_f32_16x16x32_bf16(A[t][0], Ba, acc00, 0, 0, 0);
        acc01 = __builtin_amdgcn_mfma_f32_16x16x32_bf16(A[t][1], Ba, acc01, 0, 0, 0);
        if (TWO) {
            short8 Bb;
            if (EDGEB) {
                int rb = min(n0b + lo16 + 3 * t, 211);   // clamp: garbage lanes discarded
                Bb = *(const short8*)(src + rb * HSTR + quad * 8);
            } else {
                Bb = *(const short8*)(pb + 3 * HSTR * t);
            }
            acc10 = __builtin_amdgcn_mfma_f32_16x16x32_bf16(A[t][0], Bb, acc10, 0, 0, 0);
            acc11 = __builtin_amdgcn_mfma_f32_16x16x32_bf16(A[t][1], Bb, acc11, 0, 0, 0);
        }
    }
    store_tile<false>(dst, acc00, acc01, n0a + lo16, Lout, quad);
    if (TWO) store_tile<EDGEB>(dst, acc10, acc11, n0b + lo16, Lout, quad);
}

// 13 tiles over 4 waves: wave0 {0,4} {8,12e}; wave w {w,w+4} {w+8}.
template<int LAYER>
__device__ __forceinline__ void conv_mfma(
    const ushort_t* __restrict__ src, ushort_t* __restrict__ dst,
    const ushort_t* __restrict__ wsf, const float* __restrict__ bias,
    int Lout, int lane, int wave)
{
    const int lo16 = lane & 15, quad = lane >> 4;
    short8 A[5][2];
    #pragma unroll
    for (int t = 0; t < 5; t++) {
        A[t][0] = *(const short8*)(wsf + (t * 2 + 0) * 512 + lane * 8);
        A[t][1] = *(const short8*)(wsf + (t * 2 + 1) * 512 + lane * 8);
    }
    f32x4 b0, b1;
    #pragma unroll
    for (int r = 0; r < 4; r++) { b0[r] = bias[quad * 4 + r]; b1[r] = bias[16 + quad * 4 + r]; }
    conv_tiles<true, false>(src, dst, A, b0, b1, Lout, lo16, quad, wave);
    if (wave == 0) conv_tiles<true, true>(src, dst, A, b0, b1, Lout, lo16, quad, 8);
    else           conv_tiles<false, false>(src, dst, A, b0, b1, Lout, lo16, quad, wave + 8);
}

// ---- conv1 packed-K: one B-read + 2 MFMA per 16-time tile (5 taps x 6 ch
// packed into K=30<=32; X rows at HSTR=40 inside bufB -> conflict-free reads).
// Tiles {w, w+4, w+8} per wave; wave0 also edge 12.
__device__ __forceinline__ void conv1_packed(
    const ushort_t* __restrict__ xb, ushort_t* __restrict__ dst,
    const ushort_t* __restrict__ wsf, const float* __restrict__ bias,
    int lane, int wave)
{
    const int lo16 = lane & 15, quad = lane >> 4;
    const short8 A0 = *(const short8*)(wsf + 0 * 512 + lane * 8);
    const short8 A1 = *(const short8*)(wsf + 1 * 512 + lane * 8);
    f32x4 b0, b1;
    #pragma unroll
    for (int r = 0; r < 4; r++) { b0[r] = bias[quad * 4 + r]; b1[r] = bias[16 + quad * 4 + r]; }
    f32x4 a0[3], a1[3];
    #pragma unroll
    for (int u = 0; u < 3; u++) {
        const int n = (wave + 4 * u) * 16 + lo16;
        short8 B = *(const short8*)(xb + n * HSTR + quad * 8);
        a0[u] = __builtin_amdgcn_mfma_f32_16x16x32_bf16(A0, B, b0, 0, 0, 0);
        a1[u] = __builtin_amdgcn_mfma_f32_16x16x32_bf16(A1, B, b1, 0, 0, 0);
    }
    #pragma unroll
    for (int u = 0; u < 3; u++)
        store_tile<false>(dst, a0[u], a1[u], (wave + 4 * u) * 16 + lo16, 204, quad);
    if (wave == 0) {                         // edge tile 12: rows <= 207 valid
        const int n = 192 + lo16;
        short8 B = *(const short8*)(xb + n * HSTR + quad * 8);
        f32x4 e0 = __builtin_amdgcn_mfma_f32_16x16x32_bf16(A0, B, b0, 0, 0, 0);
        f32x4 e1 = __builtin_amdgcn_mfma_f32_16x16x32_bf16(A1, B, b1, 0, 0, 0);
        store_tile<true>(dst, e0, e1, n, 204, quad);
    }
}

__global__ void __launch_bounds__(NTHREADS, 4)
rminet_conv_kernel(const float* __restrict__ x,
                   const float* __restrict__ calib,
                   const float* __restrict__ biasv,
                   const float* __restrict__ cb1, const float* __restrict__ cb2,
                   const float* __restrict__ cb3, const float* __restrict__ cb4,
                   const ushort_t* __restrict__ wsp,
                   float* __restrict__ F)
{
    __shared__ __align__(16) ushort_t smh[SMEM_HW];
    const int tid  = threadIdx.x;
    const int b    = blockIdx.x;
    const int lane = tid & 63;
    const int wave = __builtin_amdgcn_readfirstlane(tid >> 6);

    // Zero: bufA pad rows 0..3 (uint4 0..19), bufA rows 200..211 (uint4
    // 1000..1059 — replay-stability: proven necessary in R9/R10), and ALL of
    // bufB (uint4 1060..2119; covers X slots 30..39 and X rows 204..211).
    // MFMA 0*NaN = NaN; every readable byte inits.
    {
        uint4* p = (uint4*)smh;
        for (int i = tid; i < 1140; i += NTHREADS) {
            int idx = (i < 20) ? i : ((i < 80) ? 1000 + (i - 20) : 1060 + (i - 80));
            p[idx] = make_uint4(0u, 0u, 0u, 0u);
        }
    }
    __syncthreads();

    // calibrate + normalize -> packed X rows IN bufB: X[rb][t*6+c] =
    // xn[rb-4+t][c], row stride HSTR=40. Thread tid owns xn[tid], writes rows
    // rb = tid+4-t for t=0..4 (3 dwords each). t-rotation by (tid&3) spreads
    // the write banks. NOTE: X rows 0..3 alias bufB's pad rows — re-zeroed
    // after conv1 (below).
    if (tid < 200) {
        const float* xc = x + (size_t)b * 1400 + 200 + tid;
        float v[6];
        #pragma unroll
        for (int ch = 0; ch < 6; ch++) v[ch] = xc[ch * 200];
        const float MEANS[6]  = {0.042766f, 0.0081577f, -0.015818f, 9.2993f, -0.087913f, -3.3231f};
        const float INVSTD[6] = {1.f/0.4142f, 1.f/0.3522f, 1.f/0.2881f, 1.f/1.474f, 1.f/0.6553f, 1.f/0.8728f};
        float xn[6];
        #pragma unroll
        for (int i = 0; i < 6; i++) {
            float acc = biasv[i];
            #pragma unroll
            for (int jj = 0; jj < 6; jj++) {
                float m = calib[i * 6 + jj] + ((i == jj) ? 1.0f : 0.0f);
                acc = fmaf(m, v[jj], acc);
            }
            xn[i] = (acc - MEANS[i]) * INVSTD[i];
        }
        const unsigned d0 = pack2bf(xn[0], xn[1]);
        const unsigned d1 = pack2bf(xn[2], xn[3]);
        const unsigned d2 = pack2bf(xn[4], xn[5]);
        const int trot = tid & 3;
        #pragma unroll
        for (int tt = 0; tt < 5; tt++) {
            int t = tt + trot; if (t >= 5) t -= 5;
            ushort_t* qp = smh + HB + (tid + 4 - t) * HSTR + t * 6;
            *(unsigned*)(qp + 0) = d0;
            *(unsigned*)(qp + 2) = d1;
            *(unsigned*)(qp + 4) = d2;
        }
    }
    __syncthreads();

    conv1_packed(smh + HB, smh + HA, wsp + WSF_C1, cb1, lane, wave);
    __syncthreads();
    // X fully consumed. Re-zero bufB rows 0..3 (stale X data aliases conv3's
    // left-pad; this was R5's correctness bug). Disjoint from conv2's writes
    // (rows 4+); ordered before conv3's reads by the barrier after conv2.
    if (tid < 20) ((uint4*)smh)[1060 + tid] = make_uint4(0u, 0u, 0u, 0u);
    conv_mfma<2>(smh + HA, smh + HB, wsp + WSF_C2, cb2, 200, lane, wave);
    __syncthreads();
    conv_mfma<3>(smh + HB, smh + HA, wsp + WSF_C3, cb3, 196, lane, wave);
    // Re-zero bufA rows 200..203 before conv4 (stale-h1 guard; disjoint from
    // conv3's writes). Kept verbatim (replay-stability proven).
    if (tid < 20) ((uint4*)smh)[1000 + tid] = make_uint4(0u, 0u, 0u, 0u);
    __syncthreads();

    // conv4 (MFMA, M-row 0 only): h3 -> F[b][192]; 12 tiles over 4 waves:
    // tile = wave + 4*u, u=0..2. Max read row 203.
    {
        const int lo16 = lane & 15, quad = lane >> 4;
        short8 A4[5];
        #pragma unroll
        for (int t = 0; t < 5; t++)
            A4[t] = *(const short8*)(wsp + WSF_C4 + t * 512 + lane * 8);
        f32x4 acc[3];
        #pragma unroll
        for (int u = 0; u < 3; u++) acc[u] = (f32x4){0.f, 0.f, 0.f, 0.f};
        const ushort_t* p4[3];
        #pragma unroll
        for (int u = 0; u < 3; u++)
            p4[u] = smh + HA + ((wave + 4 * u) * 16 + lo16) * HSTR + quad * 8;
        #pragma unroll
        for (int t = 0; t < 5; t++) {
            #pragma unroll
            for (int u = 0; u < 3; u++) {
                short8 B = *(const short8*)(p4[u] + 3 * HSTR * t);   // row <= 203
                acc[u] = __builtin_amdgcn_mfma_f32_16x16x32_bf16(A4[t], B, acc[u], 0, 0, 0);
            }
        }
        if (quad == 0) {
            const float c4 = cb4[0];
            #pragma unroll
            for (int u = 0; u < 3; u++) {
                int n = (wave + 4 * u) * 16 + lo16;
                F[(size_t)b * 192 + n] = gelu_fast(acc[u][0] + c4);
            }
        }
    }
}

// ---- tail v3 (replay-validated): 16 items/block -> 512 blocks (2/CU,
// 8 waves/CU). lane = output channel, wave g = 4-item group.
#define TLW1 0
#define TLW2 2400
#define TLW3 3050
#define TFQ  3245
#define TZ1F 16052
#define TZVF 16884
#define TSM_FLOATS 17156

__global__ void __launch_bounds__(256)
rminet_tail_kernel(const float* __restrict__ F,
                   const float* __restrict__ lw1, const float* __restrict__ lb1,
                   const float* __restrict__ lw2, const float* __restrict__ lb2,
                   const float* __restrict__ lw3, const float* __restrict__ lb3,
                   float* __restrict__ out)
{
    __shared__ __align__(16) float smf[TSM_FLOATS];
    float4* smq = (float4*)smf;
    const int tid  = threadIdx.x;
    const int lane = tid & 63;
    const int g    = __builtin_amdgcn_readfirstlane(tid >> 6);
    const int i0   = blockIdx.x * 16;
    const int ib   = g * 4;

    for (int idx = tid; idx < 2400; idx += 256) {
        int j4 = idx / 50, c = idx - j4 * 50;
        smq[TLW1 + idx] = *(const float4*)&lw1[c * 192 + 4 * j4];
    }
    for (int idx = tid; idx < 650; idx += 256) {
        int j4 = idx / 50, c = idx - j4 * 50;
        const float* wr = lw2 + c * 50 + 4 * j4;
        float4 w;
        w.x = wr[0]; w.y = wr[1];
        w.z = (4 * j4 + 2 < 50) ? wr[2] : 0.0f;
        w.w = (4 * j4 + 3 < 50) ? wr[3] : 0.0f;
        smq[TLW2 + idx] = w;
    }
    for (int idx = tid; idx < 195; idx += 256) {
        int j4 = idx / 15, c = idx - j4 * 15;
        const float* wr = lw3 + c * 50 + 4 * j4;
        float4 w;
        w.x = wr[0]; w.y = wr[1];
        w.z = (4 * j4 + 2 < 50) ? wr[2] : 0.0f;
        w.w = (4 * j4 + 3 < 50) ? wr[3] : 0.0f;
        smq[TLW3 + idx] = w;
    }
    {
        const float4* G4 = (const float4*)F + (size_t)i0 * 48;
        for (int idx = tid; idx < 768; idx += 256) smq[TFQ + idx] = G4[idx];
    }
    if (tid < 32) smf[TZ1F + (tid >> 1) * 52 + 50 + (tid & 1)] = 0.0f;
    __syncthreads();

    const int cc = min(lane, 49);

    {   // linear1: 192 -> 50
        float a0, a1, a2, a3;
        a0 = a1 = a2 = a3 = lb1[cc];
        for (int j4 = 0; j4 < 48; j4++) {
            float4 w = smq[TLW1 + j4 * 50 + cc];
            float4 f0 = smq[TFQ + (ib + 0) * 48 + j4];
            float4 f1 = smq[TFQ + (ib + 1) * 48 + j4];
            float4 f2 = smq[TFQ + (ib + 2) * 48 + j4];
            float4 f3 = smq[TFQ + (ib + 3) * 48 + j4];
            a0 = fmaf(w.x, f0.x, fmaf(w.y, f0.y, fmaf(w.z, f0.z, fmaf(w.w, f0.w, a0))));
            a1 = fmaf(w.x, f1.x, fmaf(w.y, f1.y, fmaf(w.z, f1.z, fmaf(w.w, f1.w, a1))));
            a2 = fmaf(w.x, f2.x, fmaf(w.y, f2.y, fmaf(w.z, f2.z, fmaf(w.w, f2.w, a2))));
            a3 = fmaf(w.x, f3.x, fmaf(w.y, f3.y, fmaf(w.z, f3.z, fmaf(w.w, f3.w, a3))));
        }
        if (lane < 50) {
            smf[TZ1F + (ib + 0) * 52 + lane] = gelu_exact(a0);
            smf[TZ1F + (ib + 1) * 52 + lane] = gelu_exact(a1);
            smf[TZ1F + (ib + 2) * 52 + lane] = gelu_exact(a2);
            smf[TZ1F + (ib + 3) * 52 + lane] = gelu_exact(a3);
        }
    }

    {   // linear2: 50 -> 50 (in-place; reads precede writes in wave order)
        float a0, a1, a2, a3;
        a0 = a1 = a2 = a3 = lb2[cc];
        for (int j4 = 0; j4 < 13; j4++) {
            float4 w = smq[TLW2 + j4 * 50 + cc];
            float4 z0 = *(const float4*)&smf[TZ1F + (ib + 0) * 52 + 4 * j4];
            float4 z1 = *(const float4*)&smf[TZ1F + (ib + 1) * 52 + 4 * j4];
            float4 z2 = *(const float4*)&smf[TZ1F + (ib + 2) * 52 + 4 * j4];
            float4 z3 = *(const float4*)&smf[TZ1F + (ib + 3) * 52 + 4 * j4];
            a0 = fmaf(w.x, z0.x, fmaf(w.y, z0.y, fmaf(w.z, z0.z, fmaf(w.w, z0.w, a0))));
            a1 = fmaf(w.x, z1.x, fmaf(w.y, z1.y, fmaf(w.z, z1.z, fmaf(w.w, z1.w, a1))));
            a2 = fmaf(w.x, z2.x, fmaf(w.y, z2.y, fmaf(w.z, z2.z, fmaf(w.w, z2.w, a2))));
            a3 = fmaf(w.x, z3.x, fmaf(w.y, z3.y, fmaf(w.z, z3.z, fmaf(w.w, z3.w, a3))));
        }
        if (lane < 50) {
            smf[TZ1F + (ib + 0) * 52 + lane] = gelu_exact(a0);
            smf[TZ1F + (ib + 1) * 52 + lane] = gelu_exact(a1);
            smf[TZ1F + (ib + 2) * 52 + lane] = gelu_exact(a2);
            smf[TZ1F + (ib + 3) * 52 + lane] = gelu_exact(a3);
        }
    }

    {   // linear3: 50 -> 15, *100 -> ZV (stride 17)
        const int c3 = min(lane, 14);
        float a0, a1, a2, a3;
        a0 = a1 = a2 = a3 = lb3[c3];
        for (int j4 = 0; j4 < 13; j4++) {
            float4 w = smq[TLW3 + j4 * 15 + c3];
            float4 z0 = *(const float4*)&smf[TZ1F + (ib + 0) * 52 + 4 * j4];
            float4 z1 = *(const float4*)&smf[TZ1F + (ib + 1) * 52 + 4 * j4];
            float4 z2 = *(const float4*)&smf[TZ1F + (ib + 2) * 52 + 4 * j4];
            float4 z3 = *(const float4*)&smf[TZ1F + (ib + 3) * 52 + 4 * j4];
            a0 = fmaf(w.x, z0.x, fmaf(w.y, z0.y, fmaf(w.z, z0.z, fmaf(w.w, z0.w, a0))));
            a1 = fmaf(w.x, z1.x, fmaf(w.y, z1.y, fmaf(w.z, z1.z, fmaf(w.w, z1.w, a1))));
            a2 = fmaf(w.x, z2.x, fmaf(w.y, z2.y, fmaf(w.z, z2.z, fmaf(w.w, z2.w, a2))));
            a3 = fmaf(w.x, z3.x, fmaf(w.y, z3.y, fmaf(w.z, z3.z, fmaf(w.w, z3.w, a3))));
        }
        if (lane < 15) {
            smf[TZVF + (ib + 0) * 17 + lane] = a0 * 100.0f;
            smf[TZVF + (ib + 1) * 17 + lane] = a1 * 100.0f;
            smf[TZVF + (ib + 2) * 17 + lane] = a2 * 100.0f;
            smf[TZVF + (ib + 3) * 17 + lane] = a3 * 100.0f;
        }
    }
    __syncthreads();

    if (g == 0 && lane < 16) {
        const float* zv = &smf[TZVF + lane * 17];
        float* ob = out + (size_t)(i0 + lane) * 15;
        #pragma unroll
        for (int c = 9; c < 15; c++) ob[c] = zv[c];

        const float A00 = zv[0], A01 = zv[1], A02 = zv[2];
        const float A10 = zv[3], A11 = zv[4], A12 = zv[5];
        const float A20 = zv[6], A21 = zv[7], A22 = zv[8];
        float S00 = A00*A00 + A10*A10 + A20*A20;
        float S01 = A00*A01 + A10*A11 + A20*A21;
        float S02 = A00*A02 + A10*A12 + A20*A22;
        float S11 = A01*A01 + A11*A11 + A21*A21;
        float S12 = A01*A02 + A11*A12 + A21*A22;
        float S22 = A02*A02 + A12*A12 + A22*A22;
        float V00=1.f, V01=0.f, V02=0.f;
        float V10=0.f, V11=1.f, V12=0.f;
        float V20=0.f, V21=0.f, V22=1.f;
        #pragma unroll
        for (int sweep = 0; sweep < 8; sweep++) {
            JROT(S00, S11, S01, S02, S12, V00, V01, V10, V11, V20, V21)
            JROT(S00, S22, S02, S01, S12, V00, V02, V10, V12, V20, V22)
            JROT(S11, S22, S12, S01, S02, V01, V02, V11, V12, V21, V22)
        }
        float e0 = S00, e1 = S11, e2 = S22;
        float va0=V00, va1=V10, va2=V20;
        float vb0=V01, vb1=V11, vb2=V21;
        float vc0=V02, vc1=V12, vc2=V22;
        float sgn = 1.0f, tq;
        if (e0 < e1) { tq=e0;e0=e1;e1=tq; tq=va0;va0=vb0;vb0=tq; tq=va1;va1=vb1;vb1=tq; tq=va2;va2=vb2;vb2=tq; sgn=-sgn; }
        if (e1 < e2) { tq=e1;e1=e2;e2=tq; tq=vb0;vb0=vc0;vc0=tq; tq=vb1;vb1=vc1;vc1=tq; tq=vb2;vb2=vc2;vc2=tq; sgn=-sgn; }
        if (e0 < e1) { tq=e0;e0=e1;e1=tq; tq=va0;va0=vb0;vb0=tq; tq=va1;va1=vb1;vb1=tq; tq=va2;va2=vb2;vb2=tq; sgn=-sgn; }
        vc0 *= sgn; vc1 *= sgn; vc2 *= sgn;
        float u10 = A00*va0 + A01*va1 + A02*va2;
        float u11 = A10*va0 + A11*va1 + A12*va2;
        float u12 = A20*va0 + A21*va1 + A22*va2;
        float n1 = sqrtf(u10*u10 + u11*u11 + u12*u12);
        float rn1 = (n1 > 1e-20f) ? 1.0f / n1 : 0.0f;
        u10 *= rn1; u11 *= rn1; u12 *= rn1;
        float u20 = A00*vb0 + A01*vb1 + A02*vb2;
        float u21 = A10*vb0 + A11*vb1 + A12*vb2;
        float u22 = A20*vb0 + A21*vb1 + A22*vb2;
        float d12 = u20*u10 + u21*u11 + u22*u12;
        u20 -= d12*u10; u21 -= d12*u11; u22 -= d12*u12;
        float n2 = sqrtf(u20*u20 + u21*u21 + u22*u22);
        float rn2 = (n2 > 1e-20f) ? 1.0f / n2 : 0.0f;
        u20 *= rn2; u21 *= rn2; u22 *= rn2;
        float u30 = u11*u22 - u12*u21;
        float u31 = u12*u20 - u10*u22;
        float u32 = u10*u21 - u11*u20;
        ob[0] = u10*va0 + u20*vb0 + u30*vc0;
        ob[1] = u10*va1 + u20*vb1 + u30*vc1;
        ob[2] = u10*va2 + u20*vb2 + u30*vc2;
        ob[3] = u11*va0 + u21*vb0 + u31*vc0;
        ob[4] = u11*va1 + u21*vb1 + u31*vc1;
        ob[5] = u11*va2 + u21*vb2 + u31*vc2;
        ob[6] = u12*va0 + u22*vb0 + u32*vc0;
        ob[7] = u12*va1 + u22*vb1 + u32*vc1;
        ob[8] = u12*va2 + u22*vb2 + u32*vc2;
    }
}

extern "C" void kernel_launch(void* const* d_in, const int* in_sizes, int n_in,
                              void* d_out, int out_size, void* d_ws, size_t ws_size,
                              hipStream_t stream) {
    (void)n_in; (void)out_size; (void)ws_size;
    const float* x     = (const float*)d_in[0];
    const float* calib = (const float*)d_in[1];
    const float* biasv = (const float*)d_in[2];
    const float* cw1   = (const float*)d_in[3];
    const float* cb1   = (const float*)d_in[4];
    const float* cw2   = (const float*)d_in[5];
    const float* cb2   = (const float*)d_in[6];
    const float* cw3   = (const float*)d_in[7];
    const float* cb3   = (const float*)d_in[8];
    const float* cw4   = (const float*)d_in[9];
    const float* cb4   = (const float*)d_in[10];
    const float* lw1   = (const float*)d_in[11];
    const float* lb1   = (const float*)d_in[12];
    const float* lw2   = (const float*)d_in[13];
    const float* lb2   = (const float*)d_in[14];
    const float* lw3   = (const float*)d_in[15];
    const float* lb3   = (const float*)d_in[16];
    float* out = (float*)d_out;
    ushort_t* wsh = (ushort_t*)d_ws;
    float* Fb = (float*)((char*)d_ws + WS_F_BYTE_OFF);
    const int B = in_sizes[0] / 1400;

    hipLaunchKernelGGL(prep_kernel, dim3(27), dim3(512), 0, stream,
                       cw1, cw2, cw3, cw4, wsh);
    hipLaunchKernelGGL(rminet_conv_kernel, dim3(B), dim3(NTHREADS), 0, stream,
                       x, calib, biasv, cb1, cb2, cb3, cb4,
                       (const ushort_t*)wsh, Fb);
    hipLaunchKernelGGL(rminet_tail_kernel, dim3(B / 16), dim3(256), 0, stream,
                       (const float*)Fb, lw1, lb1, lw2, lb2, lw3, lb3, out);
}

// Round 7
// 206.292 us; speedup vs baseline: 1.1319x; 1.0113x over previous
//
#include <hip/hip_runtime.h>
#include <hip/hip_bf16.h>
#include <math.h>

#define NTHREADS 256
typedef __attribute__((ext_vector_type(8))) short short8;
typedef __attribute__((ext_vector_type(4))) float f32x4;
typedef unsigned short ushort_t;

// ---- conv kernel LDS: two time-major activation buffers hT[row=t+4][slot],
// 212 rows x stride 40 bf16 (bufA/bufB). Packed conv1 input X lives IN bufB
// at the SAME 40-slot stride, base HB (slots 0..29 = tap*6+ch; 30..39 zero).
// X rows 0..3 alias bufB's pad rows -> re-zeroed after conv1 (R5 lesson).
// FUSED TAIL (new): float region appended after the hw buffers:
//   FL[192]  : conv4 output f (gelu'd), replaces global F
//   ZP[4][52]: per-wave linear1 partials
//   Z1[52]   : gelu(linear1) (pads 50..51 zeroed)
//   Z2[52]   : gelu(linear2) (pads 50..51 zeroed)
// Total LDS 35,936 B <= 40,960 -> still 4 blocks/CU.
#define HA    0
#define HB    8480
#define HSTR  40
// float-region offsets (in FLOAT units; byte 33920 == float 8480)
#define FLo   8480
#define ZPo   8672
#define Z1o   8880
#define Z2o   8932
#define SMEM_HW_TOT 17968     // 35,936 bytes

// ws layout: 27 conv A-frags bf16 (512 hw each) at 0;
// tail-weight blob float4[3245] at byte 65536:
//   [0..2400)  lw1s [j4][50] = lw1[c][4j4..+3]
//   [2400..3050) lw2s [j4][50] (tail j zero-padded)
//   [3050..3245) lw3s [j4][15] (tail j zero-padded)
// Z (z*100, 16 floats per item) at byte 131072.
#define WSF_C1 0
#define WSF_C2 (2*512)
#define WSF_C3 (12*512)
#define WSF_C4 (22*512)
#define WS_TWB_BYTE 65536
#define WS_Z_BYTE   131072

__device__ __forceinline__ unsigned f2bf(float f) {
    unsigned u = __float_as_uint(f);
    return (u + 0x7FFFu + ((u >> 16) & 1u)) >> 16;
}

// packed f32x2 -> bf16x2 RNE; on gfx950 lowers to v_cvt_pk_bf16_f32.
__device__ __forceinline__ unsigned pack2bf(float a, float b) {
    __hip_bfloat162 h = __float22bfloat162_rn(make_float2(a, b));
    unsigned u; __builtin_memcpy(&u, &h, 4); return u;
}

// tanh-GELU, minimal-op form: gelu = x - x/(exp2(x*t)+1).
__device__ __forceinline__ float gelu_fast(float x) {
    float x2 = x * x;
    float t  = fmaf(0.10294320f, x2, 2.3022082f);
    float e  = __builtin_amdgcn_exp2f(x * t);
    float r  = __builtin_amdgcn_rcpf(e + 1.0f);
    return fmaf(-x, r, x);
}

__device__ __forceinline__ float gelu_exact(float v) {
    return 0.5f * v * (1.0f + erff(v * 0.70710678118654752f));
}

#define JROT(Spp, Sqq, Spq, Sxp, Sxq, Vp0, Vq0, Vp1, Vq1, Vp2, Vq2)          \
    if (fabsf(Spq) > 1e-18f) {                                               \
        float tau = (Sqq - Spp) / (2.0f * Spq);                              \
        float tj = copysignf(1.0f, tau) / (fabsf(tau) + sqrtf(1.0f + tau*tau)); \
        float cj = 1.0f / sqrtf(1.0f + tj*tj);                               \
        float sj = tj * cj;                                                  \
        Spp -= tj * Spq; Sqq += tj * Spq; Spq = 0.0f;                        \
        float tmp0 = Sxp; Sxp = cj*tmp0 - sj*Sxq; Sxq = sj*tmp0 + cj*Sxq;    \
        float tv;                                                            \
        tv = Vp0; Vp0 = cj*tv - sj*Vq0; Vq0 = sj*tv + cj*Vq0;                \
        tv = Vp1; Vp1 = cj*tv - sj*Vq1; Vq1 = sj*tv + cj*Vq1;                \
        tv = Vp2; Vp2 = cj*tv - sj*Vq2; Vq2 = sj*tv + cj*Vq2;                \
    }

// ---- prep: conv weights -> MFMA A-frag lane order (bf16), fids 0..26.
// fids 27..33: repack tail linear weights into the contiguous float4 blob.
__global__ void prep_kernel(const float* __restrict__ cw1,
                            const float* __restrict__ cw2,
                            const float* __restrict__ cw3,
                            const float* __restrict__ cw4,
                            const float* __restrict__ lw1,
                            const float* __restrict__ lw2,
                            const float* __restrict__ lw3,
                            ushort_t* __restrict__ ws,
                            float4* __restrict__ twb)
{
    const int fid = blockIdx.x;              // 0..33
    if (fid >= 27) {                         // tail-weight repack
        const int idx = (fid - 27) * 512 + threadIdx.x;
        if (idx < 2400) {
            int j4 = idx / 50, c = idx - 50 * j4;
            const float* p = lw1 + c * 192 + 4 * j4;
            twb[idx] = make_float4(p[0], p[1], p[2], p[3]);
        } else if (idx < 3050) {
            int r = idx - 2400, j4 = r / 50, c = r - 50 * j4;
            const float* p = lw2 + c * 50 + 4 * j4;
            float4 w;
            w.x = p[0]; w.y = p[1];
            w.z = (4 * j4 + 2 < 50) ? p[2] : 0.0f;
            w.w = (4 * j4 + 3 < 50) ? p[3] : 0.0f;
            twb[idx] = w;
        } else if (idx < 3245) {
            int r = idx - 3050, j4 = r / 15, c = r - 15 * j4;
            const float* p = lw3 + c * 50 + 4 * j4;
            float4 w;
            w.x = p[0]; w.y = p[1];
            w.z = (4 * j4 + 2 < 50) ? p[2] : 0.0f;
            w.w = (4 * j4 + 3 < 50) ? p[3] : 0.0f;
            twb[idx] = w;
        }
        return;
    }
    const int l = threadIdx.x >> 3, j = threadIdx.x & 7;
    const int lo = l & 15, q = l >> 4;
    const int k = q * 8 + j;                 // 0..31
    const int pk = ((k >> 2) & 1) * 16 + (k >> 3) * 4 + (k & 3);  // slot->och
    float v = 0.0f;
    if (fid < 2) {                           // conv1 packed-K: t=k/6, c=k%6
        int m = fid * 16 + lo;
        if (k < 30) { int t = k / 6, c = k - 6 * t; v = cw1[(m * 6 + c) * 5 + t]; }
    } else if (fid < 12) {                   // conv2
        int f = fid - 2, tap = f >> 1, Mt = f & 1, m = Mt * 16 + lo;
        v = cw2[(m * 32 + pk) * 5 + tap];
    } else if (fid < 22) {                   // conv3
        int f = fid - 12, tap = f >> 1, Mt = f & 1, m = Mt * 16 + lo;
        v = cw3[(m * 32 + pk) * 5 + tap];
    } else {                                 // conv4: M-row 0 only
        int tap = fid - 22;
        if (lo == 0) v = cw4[pk * 5 + tap];
    }
    ws[fid * 512 + l * 8 + j] = (ushort_t)f2bf(v);
}

// Permuted-slot epilogue: one ds_write_b128 per lane (slots q*8..q*8+7).
template<bool EDGE>
__device__ __forceinline__ void store_tile(
    ushort_t* __restrict__ dst, const f32x4 a0, const f32x4 a1,
    int n, int Lout, int quad)
{
    ushort_t* row = dst + (4 + n) * HSTR + quad * 8;
    if (EDGE && n >= Lout) {
        *(uint4*)row = make_uint4(0u, 0u, 0u, 0u);
    } else {
        *(uint4*)row = make_uint4(
            pack2bf(gelu_fast(a0[0]), gelu_fast(a0[1])),
            pack2bf(gelu_fast(a0[2]), gelu_fast(a0[3])),
            pack2bf(gelu_fast(a1[0]), gelu_fast(a1[1])),
            pack2bf(gelu_fast(a1[2]), gelu_fast(a1[3])));
    }
}

// ---- conv2/3: 2 tiles (pair) or 1; 5 taps, dil=3. Only tile 12 (EDGEB)
// needs the row clamp / n<Lout guard.
template<bool TWO, bool EDGEB>
__device__ __forceinline__ void conv_tiles(
    const ushort_t* __restrict__ src, ushort_t* __restrict__ dst,
    const short8 A[5][2], f32x4 b0, f32x4 b1, int Lout,
    int lo16, int quad, int t0)
{
    f32x4 acc00 = b0, acc01 = b1, acc10 = b0, acc11 = b1;
    const int n0a = t0 * 16, n0b = (t0 + 4) * 16;
    const ushort_t* pa = src + (n0a + lo16) * HSTR + quad * 8;
    const ushort_t* pb = src + (n0b + lo16) * HSTR + quad * 8;
    #pragma unroll
    for (int t = 0; t < 5; t++) {
        short8 Ba = *(const short8*)(pa + 3 * HSTR * t);
        acc00 = __builtin_amdgcn_mfma_f32_16x16x32_bf16(A[t][0], Ba, acc00, 0, 0, 0);
        acc01 = __builtin_amdgcn_mfma_f32_16x16x32_bf16(A[t][1], Ba, acc01, 0, 0, 0);
        if (TWO) {
            short8 Bb;
            if (EDGEB) {
                int rb = min(n0b + lo16 + 3 * t, 211);   // clamp
                Bb = *(const short8*)(src + rb * HSTR + quad * 8);
            } else {
                Bb = *(const short8*)(pb + 3 * HSTR * t);
            }
            acc10 = __builtin_amdgcn_mfma_f32_16x16x32_bf16(A[t][0], Bb, acc10, 0, 0, 0);
            acc11 = __builtin_amdgcn_mfma_f32_16x16x32_bf16(A[t][1], Bb, acc11, 0, 0, 0);
        }
    }
    store_tile<false>(dst, acc00, acc01, n0a + lo16, Lout, quad);
    if (TWO) store_tile<EDGEB>(dst, acc10, acc11, n0b + lo16, Lout, quad);
}

// 13 tiles over 4 waves: wave0 {0,4} {8,12e}; wave w {w,w+4} {w+8}.
template<int LAYER>
__device__ __forceinline__ void conv_mfma(
    const ushort_t* __restrict__ src, ushort_t* __restrict__ dst,
    const ushort_t* __restrict__ wsf, const float* __restrict__ bias,
    int Lout, int lane, int wave)
{
    const int lo16 = lane & 15, quad = lane >> 4;
    short8 A[5][2];
    #pragma unroll
    for (int t = 0; t < 5; t++) {
        A[t][0] = *(const short8*)(wsf + (t * 2 + 0) * 512 + lane * 8);
        A[t][1] = *(const short8*)(wsf + (t * 2 + 1) * 512 + lane * 8);
    }
    f32x4 b0, b1;
    #pragma unroll
    for (int r = 0; r < 4; r++) { b0[r] = bias[quad * 4 + r]; b1[r] = bias[16 + quad * 4 + r]; }
    conv_tiles<true, false>(src, dst, A, b0, b1, Lout, lo16, quad, wave);
    if (wave == 0) conv_tiles<true, true>(src, dst, A, b0, b1, Lout, lo16, quad, 8);
    else           conv_tiles<false, false>(src, dst, A, b0, b1, Lout, lo16, quad, wave + 8);
}

// ---- conv1 packed-K: one B-read + 2 MFMA per tile (5 taps x 6 ch, K=30).
__device__ __forceinline__ void conv1_packed(
    const ushort_t* __restrict__ xb, ushort_t* __restrict__ dst,
    const ushort_t* __restrict__ wsf, const float* __restrict__ bias,
    int lane, int wave)
{
    const int lo16 = lane & 15, quad = lane >> 4;
    const short8 A0 = *(const short8*)(wsf + 0 * 512 + lane * 8);
    const short8 A1 = *(const short8*)(wsf + 1 * 512 + lane * 8);
    f32x4 b0, b1;
    #pragma unroll
    for (int r = 0; r < 4; r++) { b0[r] = bias[quad * 4 + r]; b1[r] = bias[16 + quad * 4 + r]; }
    f32x4 a0[3], a1[3];
    #pragma unroll
    for (int u = 0; u < 3; u++) {
        const int n = (wave + 4 * u) * 16 + lo16;
        short8 B = *(const short8*)(xb + n * HSTR + quad * 8);
        a0[u] = __builtin_amdgcn_mfma_f32_16x16x32_bf16(A0, B, b0, 0, 0, 0);
        a1[u] = __builtin_amdgcn_mfma_f32_16x16x32_bf16(A1, B, b1, 0, 0, 0);
    }
    #pragma unroll
    for (int u = 0; u < 3; u++)
        store_tile<false>(dst, a0[u], a1[u], (wave + 4 * u) * 16 + lo16, 204, quad);
    if (wave == 0) {                         // edge tile 12
        const int n = 192 + lo16;
        short8 B = *(const short8*)(xb + n * HSTR + quad * 8);
        f32x4 e0 = __builtin_amdgcn_mfma_f32_16x16x32_bf16(A0, B, b0, 0, 0, 0);
        f32x4 e1 = __builtin_amdgcn_mfma_f32_16x16x32_bf16(A1, B, b1, 0, 0, 0);
        store_tile<true>(dst, e0, e1, n, 204, quad);
    }
}

__global__ void __launch_bounds__(NTHREADS, 4)
rminet_conv_kernel(const float* __restrict__ x,
                   const float* __restrict__ calib,
                   const float* __restrict__ biasv,
                   const float* __restrict__ cb1, const float* __restrict__ cb2,
                   const float* __restrict__ cb3, const float* __restrict__ cb4,
                   const ushort_t* __restrict__ wsp,
                   const float4* __restrict__ twb,
                   const float* __restrict__ lb1,
                   const float* __restrict__ lb2,
                   const float* __restrict__ lb3,
                   float* __restrict__ Z)
{
    __shared__ __align__(16) ushort_t smh[SMEM_HW_TOT];
    float* smf = (float*)smh;
    const int tid  = threadIdx.x;
    const int b    = blockIdx.x;
    const int lane = tid & 63;
    const int wave = __builtin_amdgcn_readfirstlane(tid >> 6);

    // Zero: bufA pad rows 0..3 [0..19], bufA rows 200..211 [1000..1059],
    // ALL of bufB [1060..2119]. MFMA 0*NaN = NaN; every readable byte inits.
    {
        uint4* p = (uint4*)smh;
        for (int i = tid; i < 1140; i += NTHREADS) {
            int idx = (i < 20) ? i : ((i < 80) ? 1000 + (i - 20) : 1060 + (i - 80));
            p[idx] = make_uint4(0u, 0u, 0u, 0u);
        }
    }
    __syncthreads();

    // calibrate + normalize -> packed X rows IN bufB (stride HSTR=40).
    if (tid < 200) {
        const float* xc = x + (size_t)b * 1400 + 200 + tid;
        float v[6];
        #pragma unroll
        for (int ch = 0; ch < 6; ch++) v[ch] = xc[ch * 200];
        const float MEANS[6]  = {0.042766f, 0.0081577f, -0.015818f, 9.2993f, -0.087913f, -3.3231f};
        const float INVSTD[6] = {1.f/0.4142f, 1.f/0.3522f, 1.f/0.2881f, 1.f/1.474f, 1.f/0.6553f, 1.f/0.8728f};
        float xn[6];
        #pragma unroll
        for (int i = 0; i < 6; i++) {
            float acc = biasv[i];
            #pragma unroll
            for (int jj = 0; jj < 6; jj++) {
                float m = calib[i * 6 + jj] + ((i == jj) ? 1.0f : 0.0f);
                acc = fmaf(m, v[jj], acc);
            }
            xn[i] = (acc - MEANS[i]) * INVSTD[i];
        }
        const unsigned d0 = pack2bf(xn[0], xn[1]);
        const unsigned d1 = pack2bf(xn[2], xn[3]);
        const unsigned d2 = pack2bf(xn[4], xn[5]);
        const int trot = tid & 3;
        #pragma unroll
        for (int tt = 0; tt < 5; tt++) {
            int t = tt + trot; if (t >= 5) t -= 5;
            ushort_t* qp = smh + HB + (tid + 4 - t) * HSTR + t * 6;
            *(unsigned*)(qp + 0) = d0;
            *(unsigned*)(qp + 2) = d1;
            *(unsigned*)(qp + 4) = d2;
        }
    }
    __syncthreads();

    conv1_packed(smh + HB, smh + HA, wsp + WSF_C1, cb1, lane, wave);
    __syncthreads();
    // X consumed. Re-zero bufB rows 0..3 (stale X aliases conv3's left pad;
    // R5's bug). Disjoint from conv2's writes; ordered by the next barrier.
    if (tid < 20) ((uint4*)smh)[1060 + tid] = make_uint4(0u, 0u, 0u, 0u);
    conv_mfma<2>(smh + HA, smh + HB, wsp + WSF_C2, cb2, 200, lane, wave);
    __syncthreads();
    conv_mfma<3>(smh + HB, smh + HA, wsp + WSF_C3, cb3, 196, lane, wave);
    // Re-zero bufA rows 200..203 before conv4 (stale-h1 guard).
    if (tid < 20) ((uint4*)smh)[1000 + tid] = make_uint4(0u, 0u, 0u, 0u);
    __syncthreads();

    // conv4 (MFMA, M-row 0 only): h3 -> FL[192] in LDS (fused; no global F).
    {
        const int lo16 = lane & 15, quad = lane >> 4;
        short8 A4[5];
        #pragma unroll
        for (int t = 0; t < 5; t++)
            A4[t] = *(const short8*)(wsp + WSF_C4 + t * 512 + lane * 8);
        f32x4 acc[3];
        #pragma unroll
        for (int u = 0; u < 3; u++) acc[u] = (f32x4){0.f, 0.f, 0.f, 0.f};
        const ushort_t* p4[3];
        #pragma unroll
        for (int u = 0; u < 3; u++)
            p4[u] = smh + HA + ((wave + 4 * u) * 16 + lo16) * HSTR + quad * 8;
        #pragma unroll
        for (int t = 0; t < 5; t++) {
            #pragma unroll
            for (int u = 0; u < 3; u++) {
                short8 B = *(const short8*)(p4[u] + 3 * HSTR * t);   // row <= 203
                acc[u] = __builtin_amdgcn_mfma_f32_16x16x32_bf16(A4[t], B, acc[u], 0, 0, 0);
            }
        }
        if (quad == 0) {
            const float c4 = cb4[0];
            #pragma unroll
            for (int u = 0; u < 3; u++) {
                int n = (wave + 4 * u) * 16 + lo16;
                smf[FLo + n] = gelu_fast(acc[u][0] + c4);
            }
        }
    }
    __syncthreads();

    // ---- fused tail: linear1 K-split across the 4 waves (48 each).
    // Weights stream coalesced from the prep-repacked global blob (L2-hot);
    // f broadcast from LDS. Partials -> ZP, reduce+gelu on wave 0.
    {
        const int c = (lane < 50) ? lane : 49;
        float a = (wave == 0) ? lb1[c] : 0.0f;
        const int j0 = wave * 12;
        #pragma unroll
        for (int j4 = 0; j4 < 12; j4++) {
            float4 w = twb[(j0 + j4) * 50 + c];
            float4 f = *(const float4*)&smf[FLo + (j0 + j4) * 4];
            a = fmaf(w.x, f.x, fmaf(w.y, f.y, fmaf(w.z, f.z, fmaf(w.w, f.w, a))));
        }
        if (lane < 50) smf[ZPo + wave * 52 + lane] = a;
        // zero Z1/Z2 pad cols 50..51 (read by j4=12 with zero weights; must
        // not be NaN garbage) — done by idle lanes pre-barrier.
        if (wave == 0 && (lane == 50 || lane == 51)) {
            smf[Z1o + lane] = 0.0f;
            smf[Z2o + lane] = 0.0f;
        }
    }
    __syncthreads();

    if (wave == 0) {
        // reduce + gelu -> Z1 (in-wave write-then-read pattern, as tail v3)
        if (lane < 50) {
            float s = smf[ZPo + lane] + smf[ZPo + 52 + lane]
                    + smf[ZPo + 104 + lane] + smf[ZPo + 156 + lane];
            smf[Z1o + lane] = gelu_exact(s);
        }
        {   // linear2: 50 -> 50
            const int c = (lane < 50) ? lane : 49;
            float a = lb2[c];
            #pragma unroll
            for (int j4 = 0; j4 < 13; j4++) {
                float4 w = twb[2400 + j4 * 50 + c];
                float4 zp = *(const float4*)&smf[Z1o + 4 * j4];
                a = fmaf(w.x, zp.x, fmaf(w.y, zp.y, fmaf(w.z, zp.z, fmaf(w.w, zp.w, a))));
            }
            if (lane < 50) smf[Z2o + lane] = gelu_exact(a);
        }
        {   // linear3: 50 -> 15, *100 -> Z[item]
            const int c3 = (lane < 15) ? lane : 14;
            float a = lb3[c3];
            #pragma unroll
            for (int j4 = 0; j4 < 13; j4++) {
                float4 w = twb[3050 + j4 * 15 + c3];
                float4 zp = *(const float4*)&smf[Z2o + 4 * j4];
                a = fmaf(w.x, zp.x, fmaf(w.y, zp.y, fmaf(w.z, zp.z, fmaf(w.w, zp.w, a))));
            }
            if (lane < 15) Z[(size_t)b * 16 + lane] = a * 100.0f;
        }
    }
}

// ---- SVD kernel: ONE LANE PER ITEM (fully parallel Jacobi; the old tail ran
// 16 serial SVDs on one wave per block). 8192 items -> 32 blocks x 256.
__global__ void __launch_bounds__(256)
rminet_svd_kernel(const float* __restrict__ Z, float* __restrict__ out, int B)
{
    const int i = blockIdx.x * 256 + threadIdx.x;
    if (i >= B) return;
    const float* zv = Z + (size_t)i * 16;
    float* ob = out + (size_t)i * 15;
    #pragma unroll
    for (int c = 9; c < 15; c++) ob[c] = zv[c];

    const float A00 = zv[0], A01 = zv[1], A02 = zv[2];
    const float A10 = zv[3], A11 = zv[4], A12 = zv[5];
    const float A20 = zv[6], A21 = zv[7], A22 = zv[8];
    float S00 = A00*A00 + A10*A10 + A20*A20;
    float S01 = A00*A01 + A10*A11 + A20*A21;
    float S02 = A00*A02 + A10*A12 + A20*A22;
    float S11 = A01*A01 + A11*A11 + A21*A21;
    float S12 = A01*A02 + A11*A12 + A21*A22;
    float S22 = A02*A02 + A12*A12 + A22*A22;
    float V00=1.f, V01=0.f, V02=0.f;
    float V10=0.f, V11=1.f, V12=0.f;
    float V20=0.f, V21=0.f, V22=1.f;
    #pragma unroll
    for (int sweep = 0; sweep < 8; sweep++) {
        JROT(S00, S11, S01, S02, S12, V00, V01, V10, V11, V20, V21)
        JROT(S00, S22, S02, S01, S12, V00, V02, V10, V12, V20, V22)
        JROT(S11, S22, S12, S01, S02, V01, V02, V11, V12, V21, V22)
    }
    float e0 = S00, e1 = S11, e2 = S22;
    float va0=V00, va1=V10, va2=V20;
    float vb0=V01, vb1=V11, vb2=V21;
    float vc0=V02, vc1=V12, vc2=V22;
    float sgn = 1.0f, tq;
    if (e0 < e1) { tq=e0;e0=e1;e1=tq; tq=va0;va0=vb0;vb0=tq; tq=va1;va1=vb1;vb1=tq; tq=va2;va2=vb2;vb2=tq; sgn=-sgn; }
    if (e1 < e2) { tq=e1;e1=e2;e2=tq; tq=vb0;vb0=vc0;vc0=tq; tq=vb1;vb1=vc1;vc1=tq; tq=vb2;vb2=vc2;vc2=tq; sgn=-sgn; }
    if (e0 < e1) { tq=e0;e0=e1;e1=tq; tq=va0;va0=vb0;vb0=tq; tq=va1;va1=vb1;vb1=tq; tq=va2;va2=vb2;vb2=tq; sgn=-sgn; }
    vc0 *= sgn; vc1 *= sgn; vc2 *= sgn;
    float u10 = A00*va0 + A01*va1 + A02*va2;
    float u11 = A10*va0 + A11*va1 + A12*va2;
    float u12 = A20*va0 + A21*va1 + A22*va2;
    float n1 = sqrtf(u10*u10 + u11*u11 + u12*u12);
    float rn1 = (n1 > 1e-20f) ? 1.0f / n1 : 0.0f;
    u10 *= rn1; u11 *= rn1; u12 *= rn1;
    float u20 = A00*vb0 + A01*vb1 + A02*vb2;
    float u21 = A10*vb0 + A11*vb1 + A12*vb2;
    float u22 = A20*vb0 + A21*vb1 + A22*vb2;
    float d12 = u20*u10 + u21*u11 + u22*u12;
    u20 -= d12*u10; u21 -= d12*u11; u22 -= d12*u12;
    float n2 = sqrtf(u20*u20 + u21*u21 + u22*u22);
    float rn2 = (n2 > 1e-20f) ? 1.0f / n2 : 0.0f;
    u20 *= rn2; u21 *= rn2; u22 *= rn2;
    float u30 = u11*u22 - u12*u21;
    float u31 = u12*u20 - u10*u22;
    float u32 = u10*u21 - u11*u20;
    ob[0] = u10*va0 + u20*vb0 + u30*vc0;
    ob[1] = u10*va1 + u20*vb1 + u30*vc1;
    ob[2] = u10*va2 + u20*vb2 + u30*vc2;
    ob[3] = u11*va0 + u21*vb0 + u31*vc0;
    ob[4] = u11*va1 + u21*vb1 + u31*vc1;
    ob[5] = u11*va2 + u21*vb2 + u31*vc2;
    ob[6] = u12*va0 + u22*vb0 + u32*vc0;
    ob[7] = u12*va1 + u22*vb1 + u32*vc1;
    ob[8] = u12*va2 + u22*vb2 + u32*vc2;
}

extern "C" void kernel_launch(void* const* d_in, const int* in_sizes, int n_in,
                              void* d_out, int out_size, void* d_ws, size_t ws_size,
                              hipStream_t stream) {
    (void)n_in; (void)out_size; (void)ws_size;
    const float* x     = (const float*)d_in[0];
    const float* calib = (const float*)d_in[1];
    const float* biasv = (const float*)d_in[2];
    const float* cw1   = (const float*)d_in[3];
    const float* cb1   = (const float*)d_in[4];
    const float* cw2   = (const float*)d_in[5];
    const float* cb2   = (const float*)d_in[6];
    const float* cw3   = (const float*)d_in[7];
    const float* cb3   = (const float*)d_in[8];
    const float* cw4   = (const float*)d_in[9];
    const float* cb4   = (const float*)d_in[10];
    const float* lw1   = (const float*)d_in[11];
    const float* lb1   = (const float*)d_in[12];
    const float* lw2   = (const float*)d_in[13];
    const float* lb2   = (const float*)d_in[14];
    const float* lw3   = (const float*)d_in[15];
    const float* lb3   = (const float*)d_in[16];
    float* out = (float*)d_out;
    ushort_t* wsh = (ushort_t*)d_ws;
    float4* twb = (float4*)((char*)d_ws + WS_TWB_BYTE);
    float* Zb   = (float*)((char*)d_ws + WS_Z_BYTE);
    const int B = in_sizes[0] / 1400;

    hipLaunchKernelGGL(prep_kernel, dim3(34), dim3(512), 0, stream,
                       cw1, cw2, cw3, cw4, lw1, lw2, lw3, wsh, twb);
    hipLaunchKernelGGL(rminet_conv_kernel, dim3(B), dim3(NTHREADS), 0, stream,
                       x, calib, biasv, cb1, cb2, cb3, cb4,
                       (const ushort_t*)wsh, (const float4*)twb,
                       lb1, lb2, lb3, Zb);
    hipLaunchKernelGGL(rminet_svd_kernel, dim3((B + 255) / 256), dim3(256), 0, stream,
                       (const float*)Zb, out, B);
}